// Round 1
// baseline (489.927 us; speedup 1.0000x reference)
//
#include <hip/hip_runtime.h>

typedef unsigned short u16;
typedef __bf16 bf16x8 __attribute__((ext_vector_type(8)));
typedef float floatx4 __attribute__((ext_vector_type(4)));

__device__ __forceinline__ u16 f2bf(float f) {
    unsigned u = __float_as_uint(f);
    u += 0x7fff + ((u >> 16) & 1);   // round-to-nearest-even
    return (u16)(u >> 16);
}

#define GLOAD_LDS16(g, l) __builtin_amdgcn_global_load_lds( \
    (const __attribute__((address_space(1))) void*)(g),      \
    (__attribute__((address_space(3))) void*)(l), 16, 0, 0)

// ---------------- cast x (fp32 -> bf16), row-major [32768 x 512] ----------------
__global__ void cast_f32_bf16(const float* __restrict__ in, u16* __restrict__ out) {
    size_t o = ((size_t)blockIdx.x * 256 + threadIdx.x) * 4;
    float4 v = *(const float4*)(in + o);
    unsigned w0 = (unsigned)f2bf(v.x) | ((unsigned)f2bf(v.y) << 16);
    unsigned w1 = (unsigned)f2bf(v.z) | ((unsigned)f2bf(v.w) << 16);
    *(uint2*)(out + o) = make_uint2(w0, w1);
}

// ---------------- gather conv patches: Apatch[p=(b,i,j)][k=(r1,r2,cin)] bf16 ----------------
__global__ void patch_gather(const float* __restrict__ x, u16* __restrict__ out) {
    size_t o = ((size_t)blockIdx.x * 256 + threadIdx.x) * 4;
    int p   = (int)(o >> 15);
    int kk  = (int)(o & 32767);
    int r12 = kk >> 9, cin = kk & 511;
    int r1 = r12 >> 3, r2 = r12 & 7;
    int b = p >> 6, ij = p & 63, ii = ij >> 3, jj = ij & 7;
    int n = (ii * 8 + r1) * 64 + jj * 8 + r2;
    float4 v = *(const float4*)(x + ((size_t)b * 4096 + n) * 512 + cin);
    unsigned w0 = (unsigned)f2bf(v.x) | ((unsigned)f2bf(v.y) << 16);
    unsigned w1 = (unsigned)f2bf(v.z) | ((unsigned)f2bf(v.w) << 16);
    *(uint2*)(out + o) = make_uint2(w0, w1);
}

// ---------------- transpose+cast: in fp32 [R][Cn] -> out bf16 [Cn][R] ----------------
__global__ void transpose_cast(const float* __restrict__ in, u16* __restrict__ out,
                               int R, int Cn) {
    __shared__ float tile[32][33];
    int c0 = blockIdx.x * 32, r0 = blockIdx.y * 32;
    int tx = threadIdx.x, ty = threadIdx.y;   // (32, 8)
    #pragma unroll
    for (int yy = 0; yy < 4; ++yy)
        tile[ty + yy * 8][tx] = in[(size_t)(r0 + ty + yy * 8) * Cn + c0 + tx];
    __syncthreads();
    #pragma unroll
    for (int yy = 0; yy < 4; ++yy)
        out[(size_t)(c0 + ty + yy * 8) * R + r0 + tx] = f2bf(tile[tx][ty + yy * 8]);
}

// ---------------- MFMA GEMM: C[M,N] = A[M,K] * B^T[N,K]  (bf16 in, fp32 acc) ----------------
// MODE 0: plain [M,N] store            (conv fmap; ATOMIC for split-K)
// MODE 1: q permute   c -> h=c&7, d=c>>3 ; q_f[(b*8+h)*4096+n][d]
// MODE 2: kv permute  c -> f,h,d         ; kv_f[f][(b*8+h)*64+m][d]   (ATOMIC split-K)
// MODE 3: out + bias  -> d_out[M,512]
template<int MODE, bool ATOMIC>
__global__ __launch_bounds__(256) void gemm_bt(
    const u16* __restrict__ A, const u16* __restrict__ B, float* __restrict__ out,
    int M, int N, int K, int KC, const float* __restrict__ bias)
{
    __shared__ u16 As[128 * 32];
    __shared__ u16 Bs[128 * 32];
    const int tid = threadIdx.x;
    const int wv = tid >> 6, lane = tid & 63;
    const int quad = lane >> 4, l15 = lane & 15;
    const int bm = blockIdx.y * 128, bn = blockIdx.x * 128;
    const int k0 = blockIdx.z * KC;
    const int wr = wv >> 1, wc = wv & 1;

    floatx4 acc[4][4];
    #pragma unroll
    for (int i = 0; i < 4; ++i)
        #pragma unroll
        for (int j = 0; j < 4; ++j)
            acc[i][j] = (floatx4){0.f, 0.f, 0.f, 0.f};

    for (int kt = 0; kt < KC; kt += 32) {
        const int kk = k0 + kt;
        #pragma unroll
        for (int c2 = 0; c2 < 2; ++c2) {
            int e = ((wv * 2 + c2) * 64 + lane) * 8;     // element offset in 128x32 tile
            int row = e >> 5, col = e & 31;
            const u16* ga = A + (size_t)(bm + row) * K + kk + col;
            GLOAD_LDS16(ga, &As[(wv * 2 + c2) * 512]);
            const u16* gb = B + (size_t)(bn + row) * K + kk + col;
            GLOAD_LDS16(gb, &Bs[(wv * 2 + c2) * 512]);
        }
        __syncthreads();
        bf16x8 af[4], bfr[4];
        #pragma unroll
        for (int i = 0; i < 4; ++i)
            af[i] = *(const bf16x8*)&As[(wr * 64 + i * 16 + l15) * 32 + quad * 8];
        #pragma unroll
        for (int j = 0; j < 4; ++j)
            bfr[j] = *(const bf16x8*)&Bs[(wc * 64 + j * 16 + l15) * 32 + quad * 8];
        #pragma unroll
        for (int i = 0; i < 4; ++i)
            #pragma unroll
            for (int j = 0; j < 4; ++j)
                acc[i][j] = __builtin_amdgcn_mfma_f32_16x16x32_bf16(af[i], bfr[j], acc[i][j], 0, 0, 0);
        __syncthreads();
    }

    #pragma unroll
    for (int i = 0; i < 4; ++i) {
        #pragma unroll
        for (int j = 0; j < 4; ++j) {
            #pragma unroll
            for (int r = 0; r < 4; ++r) {
                int m = bm + wr * 64 + i * 16 + quad * 4 + r;
                int n = bn + wc * 64 + j * 16 + l15;
                float v = acc[i][j][r];
                if (MODE == 0) {
                    if (ATOMIC) atomicAdd(&out[(size_t)m * N + n], v);
                    else        out[(size_t)m * N + n] = v;
                } else if (MODE == 1) {
                    int b = m >> 12, nn = m & 4095;
                    int h = n & 7, d = n >> 3;
                    out[((size_t)(b * 8 + h) * 4096 + nn) * 64 + d] = v;
                } else if (MODE == 2) {
                    int b = m >> 6, mm = m & 63;
                    int f = n >> 9, c = n & 511, h = c >> 6, d = c & 63;
                    size_t idx = (size_t)f * 262144 + ((size_t)(b * 8 + h) * 64 + mm) * 64 + d;
                    if (ATOMIC) atomicAdd(&out[idx], v);
                    else        out[idx] = v;
                } else {
                    out[(size_t)m * 512 + n] = v + bias[n];
                }
            }
        }
    }
}

// ---------------- LayerNorm over C=512 per row, output bf16 ----------------
__global__ __launch_bounds__(256) void layernorm_bf16(
    const float* __restrict__ in, u16* __restrict__ out,
    const float* __restrict__ gamma, const float* __restrict__ beta)
{
    int row = blockIdx.x, tid = threadIdx.x;
    const float* rp = in + (size_t)row * 512;
    float2 v = *(const float2*)&rp[tid * 2];
    float s = v.x + v.y, ss = v.x * v.x + v.y * v.y;
    #pragma unroll
    for (int off = 32; off > 0; off >>= 1) {
        s  += __shfl_down(s, off);
        ss += __shfl_down(ss, off);
    }
    __shared__ float red[8];
    __shared__ float stats[2];
    int wvi = tid >> 6, lane = tid & 63;
    if (lane == 0) { red[wvi * 2] = s; red[wvi * 2 + 1] = ss; }
    __syncthreads();
    if (tid == 0) {
        float S = red[0] + red[2] + red[4] + red[6];
        float SS = red[1] + red[3] + red[5] + red[7];
        float mean = S * (1.f / 512.f);
        float var = SS * (1.f / 512.f) - mean * mean;
        stats[0] = mean; stats[1] = rsqrtf(var + 1e-3f);
    }
    __syncthreads();
    float mean = stats[0], rstd = stats[1];
    float o0 = (v.x - mean) * rstd * gamma[tid * 2]     + beta[tid * 2];
    float o1 = (v.y - mean) * rstd * gamma[tid * 2 + 1] + beta[tid * 2 + 1];
    unsigned w = (unsigned)f2bf(o0) | ((unsigned)f2bf(o1) << 16);
    *(unsigned*)&out[(size_t)row * 512 + tid * 2] = w;
}

// ---------------- attention: 64 keys, softmax w/o max-shift (|s|<=~2), fp32 ----------------
__global__ __launch_bounds__(256) void attention_kernel(
    const float* __restrict__ qf, const float* __restrict__ kvf, u16* __restrict__ attn_out)
{
    __shared__ float ksh[4096];
    __shared__ float vsh[4096];
    const int bh = blockIdx.x;   // b*8 + h
    const int tid = threadIdx.x;
    for (int t = tid; t < 4096; t += 256) {
        ksh[t] = kvf[(size_t)bh * 4096 + t];
        vsh[t] = kvf[262144 + (size_t)bh * 4096 + t];
    }
    __syncthreads();
    const int nq = blockIdx.y * 256 + tid;
    const float* qp = qf + ((size_t)bh * 4096 + nq) * 64;
    float qr[64];
    #pragma unroll
    for (int i = 0; i < 16; ++i) {
        float4 t4 = ((const float4*)qp)[i];
        qr[i * 4 + 0] = t4.x; qr[i * 4 + 1] = t4.y;
        qr[i * 4 + 2] = t4.z; qr[i * 4 + 3] = t4.w;
    }
    float ac[64];
    #pragma unroll
    for (int d = 0; d < 64; ++d) ac[d] = 0.f;
    float sum = 0.f;
    for (int m = 0; m < 64; ++m) {
        const float* kr = &ksh[m * 64];
        float s = 0.f;
        #pragma unroll
        for (int d = 0; d < 64; ++d) s += qr[d] * kr[d];
        float e = __expf(s * 0.125f);
        sum += e;
        const float* vr = &vsh[m * 64];
        #pragma unroll
        for (int d = 0; d < 64; ++d) ac[d] += e * vr[d];
    }
    float inv = 1.f / sum;
    const int b = bh >> 3, h = bh & 7;
    u16* op = attn_out + ((size_t)((b << 12) + nq)) * 512 + h * 64;
    #pragma unroll
    for (int i = 0; i < 32; ++i) {
        unsigned lo = f2bf(ac[2 * i] * inv);
        unsigned hi = f2bf(ac[2 * i + 1] * inv);
        ((unsigned*)op)[i] = lo | (hi << 16);
    }
}

extern "C" void kernel_launch(void* const* d_in, const int* in_sizes, int n_in,
                              void* d_out, int out_size, void* d_ws, size_t ws_size,
                              hipStream_t stream) {
    const float* x      = (const float*)d_in[0];
    const float* Wq     = (const float*)d_in[1];
    const float* Wkv    = (const float*)d_in[2];
    const float* conv_w = (const float*)d_in[3];
    const float* gamma  = (const float*)d_in[4];
    const float* beta   = (const float*)d_in[5];
    const float* Wp     = (const float*)d_in[6];
    const float* bp     = (const float*)d_in[7];
    float* out = (float*)d_out;

    char* w = (char*)d_ws;
    const size_t MB = 1ull << 20;
    u16*   x_bf    = (u16*)(w + 0);          // 32 MB   [32768 x 512] bf16
    u16*   Apatch  = (u16*)(w + 32 * MB);    // 32 MB   [512 x 32768] bf16
    u16*   WconvT  = (u16*)(w + 64 * MB);    // 32 MB   [512 x 32768] bf16
    u16*   WqT     = (u16*)(w + 96 * MB);    // 0.5 MB  [512 x 512]
    u16*   WkvT    = (u16*)(w + 97 * MB);    // 1 MB    [1024 x 512]
    u16*   WpT     = (u16*)(w + 98 * MB);    // 0.5 MB  [512 x 512]
    float* q_f     = (float*)(w + 99 * MB);  // 64 MB   [B,NH,4096,64] fp32
    float* fmap    = (float*)(w + 163 * MB); // 1 MB    [512 x 512] fp32
    u16*   fmap_ln = (u16*)(w + 164 * MB);   // 0.5 MB  [512 x 512] bf16
    float* kv_f    = (float*)(w + 165 * MB); // 2 MB    [2][B,NH,64,64] fp32
    u16*   attn_bf = (u16*)(w + 167 * MB);   // 32 MB   [32768 x 512] bf16

    hipMemsetAsync(fmap, 0, 512 * 512 * 4, stream);
    hipMemsetAsync(kv_f, 0, 2 * 262144 * 4, stream);

    cast_f32_bf16<<<16384, 256, 0, stream>>>(x, x_bf);
    patch_gather <<<16384, 256, 0, stream>>>(x, Apatch);
    transpose_cast<<<dim3(16, 16),   dim3(32, 8), 0, stream>>>(Wq,     WqT,    512,   512);
    transpose_cast<<<dim3(32, 16),   dim3(32, 8), 0, stream>>>(Wkv,    WkvT,   512,   1024);
    transpose_cast<<<dim3(16, 1024), dim3(32, 8), 0, stream>>>(conv_w, WconvT, 32768, 512);
    transpose_cast<<<dim3(16, 16),   dim3(32, 8), 0, stream>>>(Wp,     WpT,    512,   512);

    // q = x @ Wq  -> permuted q_f
    gemm_bt<1, false><<<dim3(4, 256, 1), 256, 0, stream>>>(x_bf, WqT, q_f, 32768, 512, 512, 512, nullptr);
    // conv as patch GEMM, split-K 32
    gemm_bt<0, true><<<dim3(4, 4, 32), 256, 0, stream>>>(Apatch, WconvT, fmap, 512, 512, 32768, 1024, nullptr);
    layernorm_bf16<<<512, 256, 0, stream>>>(fmap, fmap_ln, gamma, beta);
    // kv = ln(fmap) @ Wkv, split-K 4 -> permuted kv_f
    gemm_bt<2, true><<<dim3(8, 4, 4), 256, 0, stream>>>(fmap_ln, WkvT, kv_f, 512, 1024, 512, 128, nullptr);
    attention_kernel<<<dim3(64, 16), 256, 0, stream>>>(q_f, kv_f, attn_bf);
    // final projection + bias
    gemm_bt<3, false><<<dim3(4, 256, 1), 256, 0, stream>>>(attn_bf, WpT, out, 32768, 512, 512, 512, bp);
}

// Round 2
// 385.042 us; speedup vs baseline: 1.2724x; 1.2724x over previous
//
#include <hip/hip_runtime.h>

typedef unsigned short u16;
typedef __bf16 bf16x8 __attribute__((ext_vector_type(8)));
typedef float floatx4 __attribute__((ext_vector_type(4)));

__device__ __forceinline__ u16 f2bf(float f) {
    unsigned u = __float_as_uint(f);
    u += 0x7fff + ((u >> 16) & 1);   // round-to-nearest-even
    return (u16)(u >> 16);
}

#define GLOAD_LDS16(g, l) __builtin_amdgcn_global_load_lds( \
    (const __attribute__((address_space(1))) void*)(g),      \
    (__attribute__((address_space(3))) void*)(l), 16, 0, 0)

// ---------------- cast x (fp32 -> bf16), row-major [32768 x 512] ----------------
__global__ void cast_f32_bf16(const float* __restrict__ in, u16* __restrict__ out) {
    size_t o = ((size_t)blockIdx.x * 256 + threadIdx.x) * 4;
    float4 v = *(const float4*)(in + o);
    unsigned w0 = (unsigned)f2bf(v.x) | ((unsigned)f2bf(v.y) << 16);
    unsigned w1 = (unsigned)f2bf(v.z) | ((unsigned)f2bf(v.w) << 16);
    *(uint2*)(out + o) = make_uint2(w0, w1);
}

// ---------------- transpose+cast: in fp32 [R][Cn] -> out bf16 [Cn][R] ----------------
__global__ void transpose_cast(const float* __restrict__ in, u16* __restrict__ out,
                               int R, int Cn) {
    __shared__ float tile[32][33];
    int c0 = blockIdx.x * 32, r0 = blockIdx.y * 32;
    int tx = threadIdx.x, ty = threadIdx.y;   // (32, 8)
    #pragma unroll
    for (int yy = 0; yy < 4; ++yy)
        tile[ty + yy * 8][tx] = in[(size_t)(r0 + ty + yy * 8) * Cn + c0 + tx];
    __syncthreads();
    #pragma unroll
    for (int yy = 0; yy < 4; ++yy)
        out[(size_t)(c0 + ty + yy * 8) * R + r0 + tx] = f2bf(tile[tx][ty + yy * 8]);
}

// ---------------- MFMA GEMM: C[M,N] = A[M,K] * B^T[N,K]  (bf16 in, fp32 acc) ----------------
// ASRC 0: A is plain [M,K] bf16.  ASRC 1: A rows are conv patches gathered from x_bf.
// MODE 0: split-K partial store   out[z][m*N+n]                  (conv fmap)
// MODE 1: q permute -> bf16       q_bf[(b*8+h)*4096+n][d], h=c&7, d=c>>3
// MODE 2: kv permute (atomic)     K: kv[(b*8+h)*64+m][d]; V transposed: kv[V + (b*8+h)*64+d][m]
// MODE 3: out + bias  -> d_out[M,512] fp32
template<int MODE, int ASRC>
__global__ __launch_bounds__(256) void gemm_bt(
    const u16* __restrict__ A, const u16* __restrict__ B, float* __restrict__ out,
    int M, int N, int K, int KC, const float* __restrict__ bias)
{
    __shared__ u16 As[128 * 32];
    __shared__ u16 Bs[128 * 32];
    const int tid = threadIdx.x;
    const int wv = tid >> 6, lane = tid & 63;
    const int quad = lane >> 4, l15 = lane & 15;
    const int bm = blockIdx.y * 128, bn = blockIdx.x * 128;
    const int k0 = blockIdx.z * KC;
    const int wr = wv >> 1, wc = wv & 1;

    floatx4 acc[4][4];
    #pragma unroll
    for (int i = 0; i < 4; ++i)
        #pragma unroll
        for (int j = 0; j < 4; ++j)
            acc[i][j] = (floatx4){0.f, 0.f, 0.f, 0.f};

    for (int kt = 0; kt < KC; kt += 32) {
        const int kk = k0 + kt;
        #pragma unroll
        for (int c2 = 0; c2 < 2; ++c2) {
            int e = ((wv * 2 + c2) * 64 + lane) * 8;     // element offset in 128x32 tile
            int row = e >> 5, col = e & 31;
            if (ASRC == 0) {
                const u16* ga = A + (size_t)(bm + row) * K + kk + col;
                GLOAD_LDS16(ga, &As[(wv * 2 + c2) * 512]);
            } else {
                // conv patch gather: row p=(b,ii,jj), k=(r1,r2,cin)
                int p = bm + row;
                int b = p >> 6, ij = p & 63, ii = ij >> 3, jj = ij & 7;
                int r12 = kk >> 9, r1 = r12 >> 3, r2 = r12 & 7;
                int n = (ii * 8 + r1) * 64 + jj * 8 + r2;
                const u16* ga = A + ((size_t)(b * 4096 + n)) * 512 + (kk & 511) + col;
                GLOAD_LDS16(ga, &As[(wv * 2 + c2) * 512]);
            }
            const u16* gb = B + (size_t)(bn + row) * K + kk + col;
            GLOAD_LDS16(gb, &Bs[(wv * 2 + c2) * 512]);
        }
        __syncthreads();
        bf16x8 af[4], bfr[4];
        #pragma unroll
        for (int i = 0; i < 4; ++i)
            af[i] = *(const bf16x8*)&As[(wr * 64 + i * 16 + l15) * 32 + quad * 8];
        #pragma unroll
        for (int j = 0; j < 4; ++j)
            bfr[j] = *(const bf16x8*)&Bs[(wc * 64 + j * 16 + l15) * 32 + quad * 8];
        #pragma unroll
        for (int i = 0; i < 4; ++i)
            #pragma unroll
            for (int j = 0; j < 4; ++j)
                acc[i][j] = __builtin_amdgcn_mfma_f32_16x16x32_bf16(af[i], bfr[j], acc[i][j], 0, 0, 0);
        __syncthreads();
    }

    #pragma unroll
    for (int i = 0; i < 4; ++i) {
        #pragma unroll
        for (int j = 0; j < 4; ++j) {
            #pragma unroll
            for (int r = 0; r < 4; ++r) {
                int m = bm + wr * 64 + i * 16 + quad * 4 + r;
                int n = bn + wc * 64 + j * 16 + l15;
                float v = acc[i][j][r];
                if (MODE == 0) {
                    out[(size_t)blockIdx.z * 262144 + (size_t)m * N + n] = v;
                } else if (MODE == 1) {
                    int b = m >> 12, nn = m & 4095;
                    int h = n & 7, d = n >> 3;
                    ((u16*)out)[((size_t)((b * 8 + h) * 4096 + nn)) * 64 + d] = f2bf(v);
                } else if (MODE == 2) {
                    int b = m >> 6, mm = m & 63;
                    int f = n >> 9, c = n & 511, h = c >> 6, d = c & 63;
                    size_t idx;
                    if (f == 0) idx = ((size_t)((b * 8 + h) * 64 + mm)) * 64 + d;
                    else        idx = 262144 + ((size_t)((b * 8 + h) * 64 + d)) * 64 + mm;  // V^T
                    atomicAdd(&out[idx], v);
                } else {
                    out[(size_t)m * 512 + n] = v + bias[n];
                }
            }
        }
    }
}

// ---------------- split-K reduce + LayerNorm over C=512 per row, output bf16 ----------------
__global__ __launch_bounds__(256) void reduce_ln_bf16(
    const float* __restrict__ part, u16* __restrict__ out,
    const float* __restrict__ gamma, const float* __restrict__ beta)
{
    int row = blockIdx.x, tid = threadIdx.x;
    const float* base = part + (size_t)row * 512 + tid * 2;
    float2 v = {0.f, 0.f};
    #pragma unroll
    for (int z = 0; z < 32; ++z) {
        float2 t = *(const float2*)(base + (size_t)z * 262144);
        v.x += t.x; v.y += t.y;
    }
    float s = v.x + v.y, ss = v.x * v.x + v.y * v.y;
    #pragma unroll
    for (int off = 32; off > 0; off >>= 1) {
        s  += __shfl_down(s, off);
        ss += __shfl_down(ss, off);
    }
    __shared__ float red[8];
    __shared__ float stats[2];
    int wvi = tid >> 6, lane = tid & 63;
    if (lane == 0) { red[wvi * 2] = s; red[wvi * 2 + 1] = ss; }
    __syncthreads();
    if (tid == 0) {
        float S = red[0] + red[2] + red[4] + red[6];
        float SS = red[1] + red[3] + red[5] + red[7];
        float mean = S * (1.f / 512.f);
        float var = SS * (1.f / 512.f) - mean * mean;
        stats[0] = mean; stats[1] = rsqrtf(var + 1e-3f);
    }
    __syncthreads();
    float mean = stats[0], rstd = stats[1];
    float o0 = (v.x - mean) * rstd * gamma[tid * 2]     + beta[tid * 2];
    float o1 = (v.y - mean) * rstd * gamma[tid * 2 + 1] + beta[tid * 2 + 1];
    unsigned w = (unsigned)f2bf(o0) | ((unsigned)f2bf(o1) << 16);
    *(unsigned*)&out[(size_t)row * 512 + tid * 2] = w;
}

// ---------------- MFMA attention: per block = 1 bh, 128 queries, 64 keys ----------------
// q_bf [bh][4096][64] bf16; kvf fp32: K at [bh][m][d], V^T at 262144 + [bh][d][m]
__global__ __launch_bounds__(256) void attn_mfma(
    const u16* __restrict__ qbf, const float* __restrict__ kvf, u16* __restrict__ attn_out)
{
    __shared__ u16 Ksh[64 * 64];      // [key][d]
    __shared__ u16 Vt[64 * 64];       // [d][key]
    __shared__ u16 Psh[4][32 * 64];   // per-wave P [qrow][key]
    const int bh = blockIdx.x, qt = blockIdx.y;
    const int tid = threadIdx.x;
    const int wv = tid >> 6, lane = tid & 63;
    const int quad = lane >> 4, l15 = lane & 15;

    {   // stage K (bf16) and V^T (bf16)
        const float* kb = kvf + (size_t)bh * 4096;
        const float* vb = kvf + 262144 + (size_t)bh * 4096;
        for (int t = tid; t < 2048; t += 256) {
            float2 a = ((const float2*)kb)[t];
            ((unsigned*)Ksh)[t] = (unsigned)f2bf(a.x) | ((unsigned)f2bf(a.y) << 16);
            float2 b2 = ((const float2*)vb)[t];
            ((unsigned*)Vt)[t] = (unsigned)f2bf(b2.x) | ((unsigned)f2bf(b2.y) << 16);
        }
    }
    __syncthreads();

    // Q fragments straight from global: rows q0+i*16+l15, d = ks*32+quad*8
    const u16* qb = qbf + ((size_t)bh * 4096 + qt * 128 + wv * 32) * 64;
    bf16x8 qf[2][2];
    #pragma unroll
    for (int i = 0; i < 2; ++i)
        #pragma unroll
        for (int ks = 0; ks < 2; ++ks)
            qf[i][ks] = *(const bf16x8*)(qb + (i * 16 + l15) * 64 + ks * 32 + quad * 8);

    // S = Q @ K^T  (contraction over d=64, two k-steps)
    floatx4 s[2][4];
    #pragma unroll
    for (int i = 0; i < 2; ++i)
        #pragma unroll
        for (int j = 0; j < 4; ++j)
            s[i][j] = (floatx4){0.f, 0.f, 0.f, 0.f};
    #pragma unroll
    for (int j = 0; j < 4; ++j) {
        #pragma unroll
        for (int ks = 0; ks < 2; ++ks) {
            bf16x8 kf = *(const bf16x8*)&Ksh[(j * 16 + l15) * 64 + ks * 32 + quad * 8];
            #pragma unroll
            for (int i = 0; i < 2; ++i)
                s[i][j] = __builtin_amdgcn_mfma_f32_16x16x32_bf16(qf[i][ks], kf, s[i][j], 0, 0, 0);
        }
    }

    // softmax (no max-shift: |s*scale| <~ 2): exp, write unnormalized P to LDS, row-sum
    u16* P = Psh[wv];
    float rs[2][4];
    #pragma unroll
    for (int i = 0; i < 2; ++i)
        #pragma unroll
        for (int r = 0; r < 4; ++r) rs[i][r] = 0.f;
    #pragma unroll
    for (int i = 0; i < 2; ++i)
        #pragma unroll
        for (int j = 0; j < 4; ++j)
            #pragma unroll
            for (int r = 0; r < 4; ++r) {
                float e = __expf(s[i][j][r] * 0.125f);
                rs[i][r] += e;
                P[(i * 16 + quad * 4 + r) * 64 + j * 16 + l15] = f2bf(e);
            }
    #pragma unroll
    for (int m = 1; m < 16; m <<= 1)
        #pragma unroll
        for (int i = 0; i < 2; ++i)
            #pragma unroll
            for (int r = 0; r < 4; ++r)
                rs[i][r] += __shfl_xor(rs[i][r], m);
    __syncthreads();   // P LDS write -> read ordering (and all waves aligned)

    // O = P @ V  (contraction over keys=64, two k-steps); V^T rows are d-rows
    floatx4 o[2][4];
    #pragma unroll
    for (int i = 0; i < 2; ++i)
        #pragma unroll
        for (int j = 0; j < 4; ++j)
            o[i][j] = (floatx4){0.f, 0.f, 0.f, 0.f};
    #pragma unroll
    for (int ks = 0; ks < 2; ++ks) {
        bf16x8 pf[2];
        #pragma unroll
        for (int i = 0; i < 2; ++i)
            pf[i] = *(const bf16x8*)&P[(i * 16 + l15) * 64 + ks * 32 + quad * 8];
        #pragma unroll
        for (int j = 0; j < 4; ++j) {
            bf16x8 vf = *(const bf16x8*)&Vt[(j * 16 + l15) * 64 + ks * 32 + quad * 8];
            #pragma unroll
            for (int i = 0; i < 2; ++i)
                o[i][j] = __builtin_amdgcn_mfma_f32_16x16x32_bf16(pf[i], vf, o[i][j], 0, 0, 0);
        }
    }

    // normalize + store bf16 to [b][n][h*64+d]
    const int b = bh >> 3, h = bh & 7;
    #pragma unroll
    for (int i = 0; i < 2; ++i) {
        #pragma unroll
        for (int r = 0; r < 4; ++r) {
            float inv = 1.f / rs[i][r];
            int n = qt * 128 + wv * 32 + i * 16 + quad * 4 + r;
            u16* op = attn_out + ((size_t)(b * 4096 + n)) * 512 + h * 64;
            #pragma unroll
            for (int j = 0; j < 4; ++j)
                op[j * 16 + l15] = f2bf(o[i][j][r] * inv);
        }
    }
}

extern "C" void kernel_launch(void* const* d_in, const int* in_sizes, int n_in,
                              void* d_out, int out_size, void* d_ws, size_t ws_size,
                              hipStream_t stream) {
    const float* x      = (const float*)d_in[0];
    const float* Wq     = (const float*)d_in[1];
    const float* Wkv    = (const float*)d_in[2];
    const float* conv_w = (const float*)d_in[3];
    const float* gamma  = (const float*)d_in[4];
    const float* beta   = (const float*)d_in[5];
    const float* Wp     = (const float*)d_in[6];
    const float* bp     = (const float*)d_in[7];
    float* out = (float*)d_out;

    char* w = (char*)d_ws;
    const size_t MB = 1ull << 20;
    u16*   x_bf      = (u16*)(w + 0);           // 32 MB  [32768 x 512] bf16
    u16*   WconvT    = (u16*)(w + 32 * MB);     // 32 MB  [512 x 32768] bf16
    u16*   WqT       = (u16*)(w + 64 * MB);     // 0.5 MB [512 x 512]
    u16*   WkvT      = (u16*)(w + 65 * MB);     // 1 MB   [1024 x 512]
    u16*   WpT       = (u16*)(w + 66 * MB);     // 0.5 MB [512 x 512]
    u16*   q_bf      = (u16*)(w + 67 * MB);     // 32 MB  [64][4096][64] bf16
    float* fmap_part = (float*)(w + 99 * MB);   // 32 MB  [32][512 x 512] fp32
    u16*   fmap_ln   = (u16*)(w + 131 * MB);    // 0.5 MB [512 x 512] bf16
    float* kv_f      = (float*)(w + 132 * MB);  // 2 MB   K + V^T fp32
    u16*   attn_bf   = (u16*)(w + 134 * MB);    // 32 MB  [32768 x 512] bf16

    hipMemsetAsync(kv_f, 0, 2 * 262144 * 4, stream);

    cast_f32_bf16<<<16384, 256, 0, stream>>>(x, x_bf);
    transpose_cast<<<dim3(16, 16),   dim3(32, 8), 0, stream>>>(Wq,     WqT,    512,   512);
    transpose_cast<<<dim3(32, 16),   dim3(32, 8), 0, stream>>>(Wkv,    WkvT,   512,   1024);
    transpose_cast<<<dim3(16, 1024), dim3(32, 8), 0, stream>>>(conv_w, WconvT, 32768, 512);
    transpose_cast<<<dim3(16, 16),   dim3(32, 8), 0, stream>>>(Wp,     WpT,    512,   512);

    // q = x @ Wq -> bf16 permuted [bh][n][d]
    gemm_bt<1, 0><<<dim3(4, 256, 1), 256, 0, stream>>>(x_bf, WqT, (float*)q_bf, 32768, 512, 512, 512, nullptr);
    // conv as implicit patch GEMM, split-K 32 -> partials
    gemm_bt<0, 1><<<dim3(4, 4, 32), 256, 0, stream>>>(x_bf, WconvT, fmap_part, 512, 512, 32768, 1024, nullptr);
    reduce_ln_bf16<<<512, 256, 0, stream>>>(fmap_part, fmap_ln, gamma, beta);
    // kv = ln(fmap) @ Wkv, split-K 4 -> K and V^T (atomic fp32)
    gemm_bt<2, 0><<<dim3(8, 4, 4), 256, 0, stream>>>(fmap_ln, WkvT, kv_f, 512, 1024, 512, 128, nullptr);
    attn_mfma<<<dim3(64, 32), 256, 0, stream>>>(q_bf, kv_f, attn_bf);
    // final projection + bias
    gemm_bt<3, 0><<<dim3(4, 256, 1), 256, 0, stream>>>(attn_bf, WpT, out, 32768, 512, 512, 512, bp);
}

// Round 3
// 360.744 us; speedup vs baseline: 1.3581x; 1.0674x over previous
//
#include <hip/hip_runtime.h>

typedef unsigned short u16;
typedef __bf16 bf16x8 __attribute__((ext_vector_type(8)));
typedef float floatx4 __attribute__((ext_vector_type(4)));

__device__ __forceinline__ u16 f2bf(float f) {
    unsigned u = __float_as_uint(f);
    u += 0x7fff + ((u >> 16) & 1);   // round-to-nearest-even
    return (u16)(u >> 16);
}

#define GLOAD_LDS16(g, l) __builtin_amdgcn_global_load_lds( \
    (const __attribute__((address_space(1))) void*)(g),      \
    (__attribute__((address_space(3))) void*)(l), 16, 0, 0)

// ---------------- cast x (fp32 -> bf16), row-major [32768 x 512] ----------------
__global__ void cast_f32_bf16(const float* __restrict__ in, u16* __restrict__ out) {
    size_t o = ((size_t)blockIdx.x * 256 + threadIdx.x) * 4;
    float4 v = *(const float4*)(in + o);
    unsigned w0 = (unsigned)f2bf(v.x) | ((unsigned)f2bf(v.y) << 16);
    unsigned w1 = (unsigned)f2bf(v.z) | ((unsigned)f2bf(v.w) << 16);
    *(uint2*)(out + o) = make_uint2(w0, w1);
}

// ---------------- transpose+cast: in fp32 [R][Cn] -> out bf16 [Cn][R] ----------------
__global__ void transpose_cast(const float* __restrict__ in, u16* __restrict__ out,
                               int R, int Cn) {
    __shared__ float tile[32][33];
    int c0 = blockIdx.x * 32, r0 = blockIdx.y * 32;
    int tx = threadIdx.x, ty = threadIdx.y;   // (32, 8)
    #pragma unroll
    for (int yy = 0; yy < 4; ++yy)
        tile[ty + yy * 8][tx] = in[(size_t)(r0 + ty + yy * 8) * Cn + c0 + tx];
    __syncthreads();
    #pragma unroll
    for (int yy = 0; yy < 4; ++yy)
        out[(size_t)(c0 + ty + yy * 8) * R + r0 + tx] = f2bf(tile[tx][ty + yy * 8]);
}

// ---- Wq transpose with head-major column permute: out[n'][k], n' = (c&7)*64 + (c>>3) ----
__global__ void transpose_cast_qperm(const float* __restrict__ in, u16* __restrict__ out) {
    __shared__ float tile[32][33];
    int c0 = blockIdx.x * 32, r0 = blockIdx.y * 32;
    int tx = threadIdx.x, ty = threadIdx.y;   // (32, 8)
    #pragma unroll
    for (int yy = 0; yy < 4; ++yy)
        tile[ty + yy * 8][tx] = in[(size_t)(r0 + ty + yy * 8) * 512 + c0 + tx];
    __syncthreads();
    #pragma unroll
    for (int yy = 0; yy < 4; ++yy) {
        int cc = c0 + ty + yy * 8;
        int np = (cc & 7) * 64 + (cc >> 3);
        out[(size_t)np * 512 + r0 + tx] = f2bf(tile[tx][ty + yy * 8]);
    }
}

// ---------------- MFMA GEMM: C[M,N] = A[M,K] * B^T[N,K]  (bf16 in, fp32 acc) ----------------
// BK=64 staged as two [128][32] sub-tiles per operand (keeps 64B LDS row stride).
// ASRC 0: A is plain [M,K] bf16.  ASRC 1: A rows are conv patches gathered from x_bf.
// MODE 0: split-K partial store   out[z][m*N+n]                  (conv fmap)
// MODE 1: q store (B cols pre-permuted head-major): h=n>>6, d=n&63 -> q_bf[(b*8+h)*4096+nn][d]
// MODE 2: kv permute (atomic)     K: kv[(b*8+h)*64+m][d]; V transposed: kv[V + (b*8+h)*64+d][m]
// MODE 3: out + bias  -> d_out[M,512] fp32
template<int MODE, int ASRC>
__global__ __launch_bounds__(256) void gemm_bt(
    const u16* __restrict__ A, const u16* __restrict__ B, float* __restrict__ out,
    int M, int N, int K, int KC, const float* __restrict__ bias)
{
    __shared__ u16 As[2][128 * 32];
    __shared__ u16 Bs[2][128 * 32];
    const int tid = threadIdx.x;
    const int wv = tid >> 6, lane = tid & 63;
    const int quad = lane >> 4, l15 = lane & 15;
    const int bm = blockIdx.y * 128, bn = blockIdx.x * 128;
    const int k0 = blockIdx.z * KC;
    const int wr = wv >> 1, wc = wv & 1;

    floatx4 acc[4][4];
    #pragma unroll
    for (int i = 0; i < 4; ++i)
        #pragma unroll
        for (int j = 0; j < 4; ++j)
            acc[i][j] = (floatx4){0.f, 0.f, 0.f, 0.f};

    for (int kt = 0; kt < KC; kt += 64) {
        const int kk = k0 + kt;
        #pragma unroll
        for (int hf = 0; hf < 2; ++hf) {
            #pragma unroll
            for (int c2 = 0; c2 < 2; ++c2) {
                int idx = ((wv * 2 + c2) * 64 + lane) * 8;   // element offset in [128][32] half
                int row = idx >> 5, col = idx & 31;
                int k = kk + hf * 32 + col;
                if (ASRC == 0) {
                    const u16* ga = A + (size_t)(bm + row) * K + k;
                    GLOAD_LDS16(ga, &As[hf][(wv * 2 + c2) * 512]);
                } else {
                    // conv patch gather: row p=(b,ii,jj), k=(r1,r2,cin)
                    int p = bm + row;
                    int b = p >> 6, ij = p & 63, ii = ij >> 3, jj = ij & 7;
                    int r12 = k >> 9, r1 = r12 >> 3, r2 = r12 & 7;
                    int n = (ii * 8 + r1) * 64 + jj * 8 + r2;
                    const u16* ga = A + ((size_t)(b * 4096 + n)) * 512 + (k & 511);
                    GLOAD_LDS16(ga, &As[hf][(wv * 2 + c2) * 512]);
                }
                const u16* gb = B + (size_t)(bn + row) * K + k;
                GLOAD_LDS16(gb, &Bs[hf][(wv * 2 + c2) * 512]);
            }
        }
        __syncthreads();
        #pragma unroll
        for (int ks = 0; ks < 2; ++ks) {
            bf16x8 af[4], bfr[4];
            #pragma unroll
            for (int i = 0; i < 4; ++i)
                af[i] = *(const bf16x8*)&As[ks][(wr * 64 + i * 16 + l15) * 32 + quad * 8];
            #pragma unroll
            for (int j = 0; j < 4; ++j)
                bfr[j] = *(const bf16x8*)&Bs[ks][(wc * 64 + j * 16 + l15) * 32 + quad * 8];
            #pragma unroll
            for (int i = 0; i < 4; ++i)
                #pragma unroll
                for (int j = 0; j < 4; ++j)
                    acc[i][j] = __builtin_amdgcn_mfma_f32_16x16x32_bf16(af[i], bfr[j], acc[i][j], 0, 0, 0);
        }
        __syncthreads();
    }

    #pragma unroll
    for (int i = 0; i < 4; ++i) {
        #pragma unroll
        for (int j = 0; j < 4; ++j) {
            #pragma unroll
            for (int r = 0; r < 4; ++r) {
                int m = bm + wr * 64 + i * 16 + quad * 4 + r;
                int n = bn + wc * 64 + j * 16 + l15;
                float v = acc[i][j][r];
                if (MODE == 0) {
                    out[(size_t)blockIdx.z * 262144 + (size_t)m * N + n] = v;
                } else if (MODE == 1) {
                    int b = m >> 12, nn = m & 4095;
                    int h = n >> 6, d = n & 63;     // B columns pre-permuted head-major
                    ((u16*)out)[((size_t)((b * 8 + h) * 4096 + nn)) * 64 + d] = f2bf(v);
                } else if (MODE == 2) {
                    int b = m >> 6, mm = m & 63;
                    int f = n >> 9, c = n & 511, h = c >> 6, d = c & 63;
                    size_t idx;
                    if (f == 0) idx = ((size_t)((b * 8 + h) * 64 + mm)) * 64 + d;
                    else        idx = 262144 + ((size_t)((b * 8 + h) * 64 + d)) * 64 + mm;  // V^T
                    atomicAdd(&out[idx], v);
                } else {
                    out[(size_t)m * 512 + n] = v + bias[n];
                }
            }
        }
    }
}

// ---------------- split-K reduce (64 slices) + LayerNorm over C=512, output bf16 ----------------
__global__ __launch_bounds__(256) void reduce_ln_bf16(
    const float* __restrict__ part, u16* __restrict__ out,
    const float* __restrict__ gamma, const float* __restrict__ beta)
{
    int row = blockIdx.x, tid = threadIdx.x;
    const float* base = part + (size_t)row * 512 + tid * 2;
    float2 v = {0.f, 0.f};
    #pragma unroll 8
    for (int z = 0; z < 64; ++z) {
        float2 t = *(const float2*)(base + (size_t)z * 262144);
        v.x += t.x; v.y += t.y;
    }
    float s = v.x + v.y, ss = v.x * v.x + v.y * v.y;
    #pragma unroll
    for (int off = 32; off > 0; off >>= 1) {
        s  += __shfl_down(s, off);
        ss += __shfl_down(ss, off);
    }
    __shared__ float red[8];
    __shared__ float stats[2];
    int wvi = tid >> 6, lane = tid & 63;
    if (lane == 0) { red[wvi * 2] = s; red[wvi * 2 + 1] = ss; }
    __syncthreads();
    if (tid == 0) {
        float S = red[0] + red[2] + red[4] + red[6];
        float SS = red[1] + red[3] + red[5] + red[7];
        float mean = S * (1.f / 512.f);
        float var = SS * (1.f / 512.f) - mean * mean;
        stats[0] = mean; stats[1] = rsqrtf(var + 1e-3f);
    }
    __syncthreads();
    float mean = stats[0], rstd = stats[1];
    float o0 = (v.x - mean) * rstd * gamma[tid * 2]     + beta[tid * 2];
    float o1 = (v.y - mean) * rstd * gamma[tid * 2 + 1] + beta[tid * 2 + 1];
    unsigned w = (unsigned)f2bf(o0) | ((unsigned)f2bf(o1) << 16);
    *(unsigned*)&out[(size_t)row * 512 + tid * 2] = w;
}

// ---------------- MFMA attention: per block = 1 bh, 128 queries, 64 keys ----------------
// q_bf [bh][4096][64] bf16; kvf fp32: K at [bh][m][d], V^T at 262144 + [bh][d][m]
__global__ __launch_bounds__(256) void attn_mfma(
    const u16* __restrict__ qbf, const float* __restrict__ kvf, u16* __restrict__ attn_out)
{
    __shared__ u16 Ksh[64 * 64];      // [key][d]
    __shared__ u16 Vt[64 * 64];       // [d][key]
    __shared__ u16 Psh[4][32 * 64];   // per-wave P [qrow][key]
    const int bh = blockIdx.x, qt = blockIdx.y;
    const int tid = threadIdx.x;
    const int wv = tid >> 6, lane = tid & 63;
    const int quad = lane >> 4, l15 = lane & 15;

    {   // stage K (bf16) and V^T (bf16)
        const float* kb = kvf + (size_t)bh * 4096;
        const float* vb = kvf + 262144 + (size_t)bh * 4096;
        for (int t = tid; t < 2048; t += 256) {
            float2 a = ((const float2*)kb)[t];
            ((unsigned*)Ksh)[t] = (unsigned)f2bf(a.x) | ((unsigned)f2bf(a.y) << 16);
            float2 b2 = ((const float2*)vb)[t];
            ((unsigned*)Vt)[t] = (unsigned)f2bf(b2.x) | ((unsigned)f2bf(b2.y) << 16);
        }
    }
    __syncthreads();

    // Q fragments straight from global: rows q0+i*16+l15, d = ks*32+quad*8
    const u16* qb = qbf + ((size_t)bh * 4096 + qt * 128 + wv * 32) * 64;
    bf16x8 qf[2][2];
    #pragma unroll
    for (int i = 0; i < 2; ++i)
        #pragma unroll
        for (int ks = 0; ks < 2; ++ks)
            qf[i][ks] = *(const bf16x8*)(qb + (i * 16 + l15) * 64 + ks * 32 + quad * 8);

    // S = Q @ K^T  (contraction over d=64, two k-steps)
    floatx4 s[2][4];
    #pragma unroll
    for (int i = 0; i < 2; ++i)
        #pragma unroll
        for (int j = 0; j < 4; ++j)
            s[i][j] = (floatx4){0.f, 0.f, 0.f, 0.f};
    #pragma unroll
    for (int j = 0; j < 4; ++j) {
        #pragma unroll
        for (int ks = 0; ks < 2; ++ks) {
            bf16x8 kf = *(const bf16x8*)&Ksh[(j * 16 + l15) * 64 + ks * 32 + quad * 8];
            #pragma unroll
            for (int i = 0; i < 2; ++i)
                s[i][j] = __builtin_amdgcn_mfma_f32_16x16x32_bf16(qf[i][ks], kf, s[i][j], 0, 0, 0);
        }
    }

    // softmax (no max-shift: |s*scale| <~ 2): exp, write unnormalized P to LDS, row-sum
    u16* P = Psh[wv];
    float rs[2][4];
    #pragma unroll
    for (int i = 0; i < 2; ++i)
        #pragma unroll
        for (int r = 0; r < 4; ++r) rs[i][r] = 0.f;
    #pragma unroll
    for (int i = 0; i < 2; ++i)
        #pragma unroll
        for (int j = 0; j < 4; ++j)
            #pragma unroll
            for (int r = 0; r < 4; ++r) {
                float e = __expf(s[i][j][r] * 0.125f);
                rs[i][r] += e;
                P[(i * 16 + quad * 4 + r) * 64 + j * 16 + l15] = f2bf(e);
            }
    #pragma unroll
    for (int m = 1; m < 16; m <<= 1)
        #pragma unroll
        for (int i = 0; i < 2; ++i)
            #pragma unroll
            for (int r = 0; r < 4; ++r)
                rs[i][r] += __shfl_xor(rs[i][r], m);
    __syncthreads();   // P LDS write -> read ordering

    // O = P @ V  (contraction over keys=64, two k-steps); V^T rows are d-rows
    floatx4 o[2][4];
    #pragma unroll
    for (int i = 0; i < 2; ++i)
        #pragma unroll
        for (int j = 0; j < 4; ++j)
            o[i][j] = (floatx4){0.f, 0.f, 0.f, 0.f};
    #pragma unroll
    for (int ks = 0; ks < 2; ++ks) {
        bf16x8 pf[2];
        #pragma unroll
        for (int i = 0; i < 2; ++i)
            pf[i] = *(const bf16x8*)&P[(i * 16 + l15) * 64 + ks * 32 + quad * 8];
        #pragma unroll
        for (int j = 0; j < 4; ++j) {
            bf16x8 vf = *(const bf16x8*)&Vt[(j * 16 + l15) * 64 + ks * 32 + quad * 8];
            #pragma unroll
            for (int i = 0; i < 2; ++i)
                o[i][j] = __builtin_amdgcn_mfma_f32_16x16x32_bf16(pf[i], vf, o[i][j], 0, 0, 0);
        }
    }

    // normalize + store bf16 to [b][n][h*64+d]
    const int b = bh >> 3, h = bh & 7;
    #pragma unroll
    for (int i = 0; i < 2; ++i) {
        #pragma unroll
        for (int r = 0; r < 4; ++r) {
            float inv = 1.f / rs[i][r];
            int n = qt * 128 + wv * 32 + i * 16 + quad * 4 + r;
            u16* op = attn_out + ((size_t)(b * 4096 + n)) * 512 + h * 64;
            #pragma unroll
            for (int j = 0; j < 4; ++j)
                op[j * 16 + l15] = f2bf(o[i][j][r] * inv);
        }
    }
}

extern "C" void kernel_launch(void* const* d_in, const int* in_sizes, int n_in,
                              void* d_out, int out_size, void* d_ws, size_t ws_size,
                              hipStream_t stream) {
    const float* x      = (const float*)d_in[0];
    const float* Wq     = (const float*)d_in[1];
    const float* Wkv    = (const float*)d_in[2];
    const float* conv_w = (const float*)d_in[3];
    const float* gamma  = (const float*)d_in[4];
    const float* beta   = (const float*)d_in[5];
    const float* Wp     = (const float*)d_in[6];
    const float* bp     = (const float*)d_in[7];
    float* out = (float*)d_out;

    char* w = (char*)d_ws;
    const size_t MB = 1ull << 20;
    u16*   x_bf      = (u16*)(w + 0);           // 32 MB  [32768 x 512] bf16
    u16*   WconvT    = (u16*)(w + 32 * MB);     // 32 MB  [512 x 32768] bf16
    u16*   WqTp      = (u16*)(w + 64 * MB);     // 0.5 MB [512 x 512] (head-major cols)
    u16*   WkvT      = (u16*)(w + 65 * MB);     // 1 MB   [1024 x 512]
    u16*   WpT       = (u16*)(w + 66 * MB);     // 0.5 MB [512 x 512]
    u16*   q_bf      = (u16*)(w + 67 * MB);     // 32 MB  [64][4096][64] bf16
    float* fmap_part = (float*)(w + 99 * MB);   // 64 MB  [64][512 x 512] fp32
    u16*   fmap_ln   = (u16*)(w + 163 * MB);    // 0.5 MB [512 x 512] bf16
    float* kv_f      = (float*)(w + 164 * MB);  // 2 MB   K + V^T fp32
    u16*   attn_bf   = (u16*)(w + 166 * MB);    // 32 MB  [32768 x 512] bf16

    hipMemsetAsync(kv_f, 0, 2 * 262144 * 4, stream);

    cast_f32_bf16<<<16384, 256, 0, stream>>>(x, x_bf);
    transpose_cast_qperm<<<dim3(16, 16), dim3(32, 8), 0, stream>>>(Wq, WqTp);
    transpose_cast<<<dim3(32, 16),   dim3(32, 8), 0, stream>>>(Wkv,    WkvT,   512,   1024);
    transpose_cast<<<dim3(16, 1024), dim3(32, 8), 0, stream>>>(conv_w, WconvT, 32768, 512);
    transpose_cast<<<dim3(16, 16),   dim3(32, 8), 0, stream>>>(Wp,     WpT,    512,   512);

    // q = x @ Wq -> bf16 permuted [bh][n][d] (coalesced via pre-permuted B cols)
    gemm_bt<1, 0><<<dim3(4, 256, 1), 256, 0, stream>>>(x_bf, WqTp, (float*)q_bf, 32768, 512, 512, 512, nullptr);
    // conv as implicit patch GEMM, split-K 64 -> partials
    gemm_bt<0, 1><<<dim3(4, 4, 64), 256, 0, stream>>>(x_bf, WconvT, fmap_part, 512, 512, 32768, 512, nullptr);
    reduce_ln_bf16<<<512, 256, 0, stream>>>(fmap_part, fmap_ln, gamma, beta);
    // kv = ln(fmap) @ Wkv, split-K 4 -> K and V^T (atomic fp32)
    gemm_bt<2, 0><<<dim3(8, 4, 4), 256, 0, stream>>>(fmap_ln, WkvT, kv_f, 512, 1024, 512, 128, nullptr);
    attn_mfma<<<dim3(64, 32), 256, 0, stream>>>(q_bf, kv_f, attn_bf);
    // final projection + bias
    gemm_bt<3, 0><<<dim3(4, 256, 1), 256, 0, stream>>>(attn_bf, WpT, out, 32768, 512, 512, 512, bp);
}

// Round 4
// 335.320 us; speedup vs baseline: 1.4611x; 1.0758x over previous
//
#include <hip/hip_runtime.h>

typedef unsigned short u16;
typedef __bf16 bf16x8 __attribute__((ext_vector_type(8)));
typedef float floatx4 __attribute__((ext_vector_type(4)));

__device__ __forceinline__ u16 f2bf(float f) {
    unsigned u = __float_as_uint(f);
    u += 0x7fff + ((u >> 16) & 1);   // round-to-nearest-even
    return (u16)(u >> 16);
}

#define GLOAD_LDS16(g, l) __builtin_amdgcn_global_load_lds( \
    (const __attribute__((address_space(1))) void*)(g),      \
    (__attribute__((address_space(3))) void*)(l), 16, 0, 0)

// ---------------- prep: cast x + all 4 weight transposes, one launch ----------------
// blocks [0,16384): cast x fp32->bf16
// blocks [16384,32768): conv_w transpose (R=32768,Cn=512)
// next 256: Wq transpose with head-major col permute; next 256: Wp; next 512: Wkv (Cn=1024)
__global__ __launch_bounds__(256) void prep_kernel(
    const float* __restrict__ x, u16* __restrict__ x_bf,
    const float* __restrict__ conv_w, u16* __restrict__ WconvT,
    const float* __restrict__ Wq, u16* __restrict__ WqTp,
    const float* __restrict__ Wp, u16* __restrict__ WpT,
    const float* __restrict__ Wkv, u16* __restrict__ WkvT)
{
    int blk = blockIdx.x;
    const int tid = threadIdx.x;
    if (blk < 16384) {
        size_t o = ((size_t)blk * 256 + tid) * 4;
        float4 v = *(const float4*)(x + o);
        unsigned w0 = (unsigned)f2bf(v.x) | ((unsigned)f2bf(v.y) << 16);
        unsigned w1 = (unsigned)f2bf(v.z) | ((unsigned)f2bf(v.w) << 16);
        *(uint2*)(x_bf + o) = make_uint2(w0, w1);
        return;
    }
    blk -= 16384;
    const float* in; u16* outp; int R, Cn, bx, by; bool perm = false;
    if (blk < 16384)      { in = conv_w; outp = WconvT; R = 32768; Cn = 512;  bx = blk & 15; by = blk >> 4; }
    else if (blk < 16640) { blk -= 16384; in = Wq;  outp = WqTp; R = 512; Cn = 512;  bx = blk & 15; by = blk >> 4; perm = true; }
    else if (blk < 16896) { blk -= 16640; in = Wp;  outp = WpT;  R = 512; Cn = 512;  bx = blk & 15; by = blk >> 4; }
    else                  { blk -= 16896; in = Wkv; outp = WkvT; R = 512; Cn = 1024; bx = blk & 31; by = blk >> 5; }
    __shared__ float tile[32][33];
    const int c0 = bx * 32, r0 = by * 32;
    const int tx = tid & 31, ty = tid >> 5;
    #pragma unroll
    for (int yy = 0; yy < 4; ++yy)
        tile[ty + yy * 8][tx] = in[(size_t)(r0 + ty + yy * 8) * Cn + c0 + tx];
    __syncthreads();
    #pragma unroll
    for (int yy = 0; yy < 4; ++yy) {
        int cc = c0 + ty + yy * 8;
        int np = perm ? ((cc & 7) * 64 + (cc >> 3)) : cc;
        outp[(size_t)np * R + r0 + tx] = f2bf(tile[tx][ty + yy * 8]);
    }
}

// ---------------- MFMA GEMM: C[M,N] = A[M,K] * B^T[N,K]  (bf16 in, fp32 acc) ----------------
// BK=64 staged as two [128][32] sub-tiles per operand (keeps 64B LDS row stride).
// ASRC 0: A is plain [M,K] bf16.  ASRC 1: A rows are conv patches gathered from x_bf.
// MODE 0: split-K partial store bf16  ((u16*)out)[z*262144 + m*512 + n]   (conv fmap)
// MODE 1: q store (B cols pre-permuted head-major): h=n>>6, d=n&63 -> q_bf[(b*8+h)*4096+nn][d]
// MODE 2: kv permute (plain store)  K: kv[(b*8+h)*64+m][d]; V transposed: kv[V + (b*8+h)*64+d][m]
// MODE 3: out + bias  -> d_out[M,512] fp32
template<int MODE, int ASRC>
__global__ __launch_bounds__(256) void gemm_bt(
    const u16* __restrict__ A, const u16* __restrict__ B, float* __restrict__ out,
    int M, int N, int K, int KC, const float* __restrict__ bias)
{
    __shared__ u16 As[2][128 * 32];
    __shared__ u16 Bs[2][128 * 32];
    const int tid = threadIdx.x;
    const int wv = tid >> 6, lane = tid & 63;
    const int quad = lane >> 4, l15 = lane & 15;
    const int bm = blockIdx.y * 128, bn = blockIdx.x * 128;
    const int k0 = blockIdx.z * KC;
    const int wr = wv >> 1, wc = wv & 1;

    floatx4 acc[4][4];
    #pragma unroll
    for (int i = 0; i < 4; ++i)
        #pragma unroll
        for (int j = 0; j < 4; ++j)
            acc[i][j] = (floatx4){0.f, 0.f, 0.f, 0.f};

    for (int kt = 0; kt < KC; kt += 64) {
        const int kk = k0 + kt;
        #pragma unroll
        for (int hf = 0; hf < 2; ++hf) {
            #pragma unroll
            for (int c2 = 0; c2 < 2; ++c2) {
                int idx = ((wv * 2 + c2) * 64 + lane) * 8;   // element offset in [128][32] half
                int row = idx >> 5, col = idx & 31;
                int k = kk + hf * 32 + col;
                if (ASRC == 0) {
                    const u16* ga = A + (size_t)(bm + row) * K + k;
                    GLOAD_LDS16(ga, &As[hf][(wv * 2 + c2) * 512]);
                } else {
                    // conv patch gather: row p=(b,ii,jj), k=(r1,r2,cin)
                    int p = bm + row;
                    int b = p >> 6, ij = p & 63, ii = ij >> 3, jj = ij & 7;
                    int r12 = k >> 9, r1 = r12 >> 3, r2 = r12 & 7;
                    int n = (ii * 8 + r1) * 64 + jj * 8 + r2;
                    const u16* ga = A + ((size_t)(b * 4096 + n)) * 512 + (k & 511);
                    GLOAD_LDS16(ga, &As[hf][(wv * 2 + c2) * 512]);
                }
                const u16* gb = B + (size_t)(bn + row) * K + k;
                GLOAD_LDS16(gb, &Bs[hf][(wv * 2 + c2) * 512]);
            }
        }
        __syncthreads();
        #pragma unroll
        for (int ks = 0; ks < 2; ++ks) {
            bf16x8 af[4], bfr[4];
            #pragma unroll
            for (int i = 0; i < 4; ++i)
                af[i] = *(const bf16x8*)&As[ks][(wr * 64 + i * 16 + l15) * 32 + quad * 8];
            #pragma unroll
            for (int j = 0; j < 4; ++j)
                bfr[j] = *(const bf16x8*)&Bs[ks][(wc * 64 + j * 16 + l15) * 32 + quad * 8];
            #pragma unroll
            for (int i = 0; i < 4; ++i)
                #pragma unroll
                for (int j = 0; j < 4; ++j)
                    acc[i][j] = __builtin_amdgcn_mfma_f32_16x16x32_bf16(af[i], bfr[j], acc[i][j], 0, 0, 0);
        }
        __syncthreads();
    }

    #pragma unroll
    for (int i = 0; i < 4; ++i) {
        #pragma unroll
        for (int j = 0; j < 4; ++j) {
            #pragma unroll
            for (int r = 0; r < 4; ++r) {
                int m = bm + wr * 64 + i * 16 + quad * 4 + r;
                int n = bn + wc * 64 + j * 16 + l15;
                float v = acc[i][j][r];
                if (MODE == 0) {
                    ((u16*)out)[(size_t)blockIdx.z * 262144 + (size_t)m * N + n] = f2bf(v);
                } else if (MODE == 1) {
                    int b = m >> 12, nn = m & 4095;
                    int h = n >> 6, d = n & 63;     // B columns pre-permuted head-major
                    ((u16*)out)[((size_t)((b * 8 + h) * 4096 + nn)) * 64 + d] = f2bf(v);
                } else if (MODE == 2) {
                    int b = m >> 6, mm = m & 63;
                    int f = n >> 9, c = n & 511, h = c >> 6, d = c & 63;
                    size_t idx;
                    if (f == 0) idx = ((size_t)((b * 8 + h) * 64 + mm)) * 64 + d;
                    else        idx = 262144 + ((size_t)((b * 8 + h) * 64 + d)) * 64 + mm;  // V^T
                    out[idx] = v;
                } else {
                    out[(size_t)m * 512 + n] = v + bias[n];
                }
            }
        }
    }
}

// ---------------- split-K reduce (64 bf16 slices) + LayerNorm over C=512, output bf16 ----------------
__global__ __launch_bounds__(256) void reduce_ln_bf16(
    const u16* __restrict__ part, u16* __restrict__ out,
    const float* __restrict__ gamma, const float* __restrict__ beta)
{
    int row = blockIdx.x, tid = threadIdx.x;
    const unsigned* base = (const unsigned*)(part + (size_t)row * 512) + tid;
    float2 v = {0.f, 0.f};
    #pragma unroll 8
    for (int z = 0; z < 64; ++z) {
        unsigned u = base[(size_t)z * 131072];   // 262144 u16 = 131072 dwords per slice
        v.x += __uint_as_float(u << 16);
        v.y += __uint_as_float(u & 0xffff0000u);
    }
    float s = v.x + v.y, ss = v.x * v.x + v.y * v.y;
    #pragma unroll
    for (int off = 32; off > 0; off >>= 1) {
        s  += __shfl_down(s, off);
        ss += __shfl_down(ss, off);
    }
    __shared__ float red[8];
    __shared__ float stats[2];
    int wvi = tid >> 6, lane = tid & 63;
    if (lane == 0) { red[wvi * 2] = s; red[wvi * 2 + 1] = ss; }
    __syncthreads();
    if (tid == 0) {
        float S = red[0] + red[2] + red[4] + red[6];
        float SS = red[1] + red[3] + red[5] + red[7];
        float mean = S * (1.f / 512.f);
        float var = SS * (1.f / 512.f) - mean * mean;
        stats[0] = mean; stats[1] = rsqrtf(var + 1e-3f);
    }
    __syncthreads();
    float mean = stats[0], rstd = stats[1];
    float o0 = (v.x - mean) * rstd * gamma[tid * 2]     + beta[tid * 2];
    float o1 = (v.y - mean) * rstd * gamma[tid * 2 + 1] + beta[tid * 2 + 1];
    unsigned w = (unsigned)f2bf(o0) | ((unsigned)f2bf(o1) << 16);
    *(unsigned*)&out[(size_t)row * 512 + tid * 2] = w;
}

// ---------------- MFMA attention: per block = 1 bh, 128 queries, 64 keys ----------------
// q_bf [bh][4096][64] bf16; kvf fp32: K at [bh][m][d], V^T at 262144 + [bh][d][m]
__global__ __launch_bounds__(256) void attn_mfma(
    const u16* __restrict__ qbf, const float* __restrict__ kvf, u16* __restrict__ attn_out)
{
    __shared__ u16 Ksh[64 * 64];      // [key][d]
    __shared__ u16 Vt[64 * 64];       // [d][key]
    __shared__ u16 Psh[4][32 * 64];   // per-wave P [qrow][key]
    const int bh = blockIdx.x, qt = blockIdx.y;
    const int tid = threadIdx.x;
    const int wv = tid >> 6, lane = tid & 63;
    const int quad = lane >> 4, l15 = lane & 15;

    {   // stage K (bf16) and V^T (bf16)
        const float* kb = kvf + (size_t)bh * 4096;
        const float* vb = kvf + 262144 + (size_t)bh * 4096;
        for (int t = tid; t < 2048; t += 256) {
            float2 a = ((const float2*)kb)[t];
            ((unsigned*)Ksh)[t] = (unsigned)f2bf(a.x) | ((unsigned)f2bf(a.y) << 16);
            float2 b2 = ((const float2*)vb)[t];
            ((unsigned*)Vt)[t] = (unsigned)f2bf(b2.x) | ((unsigned)f2bf(b2.y) << 16);
        }
    }
    __syncthreads();

    // Q fragments straight from global: rows q0+i*16+l15, d = ks*32+quad*8
    const u16* qb = qbf + ((size_t)bh * 4096 + qt * 128 + wv * 32) * 64;
    bf16x8 qf[2][2];
    #pragma unroll
    for (int i = 0; i < 2; ++i)
        #pragma unroll
        for (int ks = 0; ks < 2; ++ks)
            qf[i][ks] = *(const bf16x8*)(qb + (i * 16 + l15) * 64 + ks * 32 + quad * 8);

    // S = Q @ K^T  (contraction over d=64, two k-steps)
    floatx4 s[2][4];
    #pragma unroll
    for (int i = 0; i < 2; ++i)
        #pragma unroll
        for (int j = 0; j < 4; ++j)
            s[i][j] = (floatx4){0.f, 0.f, 0.f, 0.f};
    #pragma unroll
    for (int j = 0; j < 4; ++j) {
        #pragma unroll
        for (int ks = 0; ks < 2; ++ks) {
            bf16x8 kf = *(const bf16x8*)&Ksh[(j * 16 + l15) * 64 + ks * 32 + quad * 8];
            #pragma unroll
            for (int i = 0; i < 2; ++i)
                s[i][j] = __builtin_amdgcn_mfma_f32_16x16x32_bf16(qf[i][ks], kf, s[i][j], 0, 0, 0);
        }
    }

    // softmax (no max-shift: |s*scale| <~ 2): exp, write unnormalized P to LDS, row-sum
    u16* P = Psh[wv];
    float rs[2][4];
    #pragma unroll
    for (int i = 0; i < 2; ++i)
        #pragma unroll
        for (int r = 0; r < 4; ++r) rs[i][r] = 0.f;
    #pragma unroll
    for (int i = 0; i < 2; ++i)
        #pragma unroll
        for (int j = 0; j < 4; ++j)
            #pragma unroll
            for (int r = 0; r < 4; ++r) {
                float e = __expf(s[i][j][r] * 0.125f);
                rs[i][r] += e;
                P[(i * 16 + quad * 4 + r) * 64 + j * 16 + l15] = f2bf(e);
            }
    #pragma unroll
    for (int m = 1; m < 16; m <<= 1)
        #pragma unroll
        for (int i = 0; i < 2; ++i)
            #pragma unroll
            for (int r = 0; r < 4; ++r)
                rs[i][r] += __shfl_xor(rs[i][r], m);
    __syncthreads();   // P LDS write -> read ordering

    // O = P @ V  (contraction over keys=64, two k-steps); V^T rows are d-rows
    floatx4 o[2][4];
    #pragma unroll
    for (int i = 0; i < 2; ++i)
        #pragma unroll
        for (int j = 0; j < 4; ++j)
            o[i][j] = (floatx4){0.f, 0.f, 0.f, 0.f};
    #pragma unroll
    for (int ks = 0; ks < 2; ++ks) {
        bf16x8 pf[2];
        #pragma unroll
        for (int i = 0; i < 2; ++i)
            pf[i] = *(const bf16x8*)&P[(i * 16 + l15) * 64 + ks * 32 + quad * 8];
        #pragma unroll
        for (int j = 0; j < 4; ++j) {
            bf16x8 vf = *(const bf16x8*)&Vt[(j * 16 + l15) * 64 + ks * 32 + quad * 8];
            #pragma unroll
            for (int i = 0; i < 2; ++i)
                o[i][j] = __builtin_amdgcn_mfma_f32_16x16x32_bf16(pf[i], vf, o[i][j], 0, 0, 0);
        }
    }

    // normalize + store bf16 to [b][n][h*64+d]
    const int b = bh >> 3, h = bh & 7;
    #pragma unroll
    for (int i = 0; i < 2; ++i) {
        #pragma unroll
        for (int r = 0; r < 4; ++r) {
            float inv = 1.f / rs[i][r];
            int n = qt * 128 + wv * 32 + i * 16 + quad * 4 + r;
            u16* op = attn_out + ((size_t)(b * 4096 + n)) * 512 + h * 64;
            #pragma unroll
            for (int j = 0; j < 4; ++j)
                op[j * 16 + l15] = f2bf(o[i][j][r] * inv);
        }
    }
}

extern "C" void kernel_launch(void* const* d_in, const int* in_sizes, int n_in,
                              void* d_out, int out_size, void* d_ws, size_t ws_size,
                              hipStream_t stream) {
    const float* x      = (const float*)d_in[0];
    const float* Wq     = (const float*)d_in[1];
    const float* Wkv    = (const float*)d_in[2];
    const float* conv_w = (const float*)d_in[3];
    const float* gamma  = (const float*)d_in[4];
    const float* beta   = (const float*)d_in[5];
    const float* Wp     = (const float*)d_in[6];
    const float* bp     = (const float*)d_in[7];
    float* out = (float*)d_out;

    char* w = (char*)d_ws;
    const size_t MB = 1ull << 20;
    u16*   x_bf      = (u16*)(w + 0);           // 32 MB  [32768 x 512] bf16
    u16*   WconvT    = (u16*)(w + 32 * MB);     // 32 MB  [512 x 32768] bf16
    u16*   WqTp      = (u16*)(w + 64 * MB);     // 0.5 MB [512 x 512] (head-major cols)
    u16*   WkvT      = (u16*)(w + 65 * MB);     // 1 MB   [1024 x 512]
    u16*   WpT       = (u16*)(w + 66 * MB);     // 0.5 MB [512 x 512]
    u16*   q_bf      = (u16*)(w + 67 * MB);     // 32 MB  [64][4096][64] bf16
    u16*   fmap_part = (u16*)(w + 99 * MB);     // 32 MB  [64][512 x 512] bf16
    u16*   fmap_ln   = (u16*)(w + 131 * MB);    // 0.5 MB [512 x 512] bf16
    float* kv_f      = (float*)(w + 132 * MB);  // 2 MB   K + V^T fp32
    u16*   attn_bf   = (u16*)(w + 134 * MB);    // 32 MB  [32768 x 512] bf16

    prep_kernel<<<33792, 256, 0, stream>>>(x, x_bf, conv_w, WconvT, Wq, WqTp, Wp, WpT, Wkv, WkvT);

    // q = x @ Wq -> bf16 permuted [bh][n][d] (coalesced via pre-permuted B cols)
    gemm_bt<1, 0><<<dim3(4, 256, 1), 256, 0, stream>>>(x_bf, WqTp, (float*)q_bf, 32768, 512, 512, 512, nullptr);
    // conv as implicit patch GEMM, split-K 64 -> bf16 partials
    gemm_bt<0, 1><<<dim3(4, 4, 64), 256, 0, stream>>>(x_bf, WconvT, (float*)fmap_part, 512, 512, 32768, 512, nullptr);
    reduce_ln_bf16<<<512, 256, 0, stream>>>(fmap_part, fmap_ln, gamma, beta);
    // kv = ln(fmap) @ Wkv -> K and V^T (plain stores, no split-K)
    gemm_bt<2, 0><<<dim3(8, 4, 1), 256, 0, stream>>>(fmap_ln, WkvT, kv_f, 512, 1024, 512, 512, nullptr);
    attn_mfma<<<dim3(64, 32), 256, 0, stream>>>(q_bf, kv_f, attn_bf);
    // final projection + bias
    gemm_bt<3, 0><<<dim3(4, 256, 1), 256, 0, stream>>>(attn_bf, WpT, out, 32768, 512, 512, 512, bp);
}